// Round 9
// baseline (153.581 us; speedup 1.0000x reference)
//
#include <hip/hip_runtime.h>

#define CC 8
#define HH 256
#define WW 512
#define KK 9
#define SEGW 128
#define XROW 136   // 4 left halo + 128 body + 4 right halo

__global__ __launch_bounds__(256, 4) void dynfilter_kernel(
    const float* __restrict__ x,
    const float* __restrict__ filt,
    const float* __restrict__ fbias,
    float* __restrict__ out)
{
    __shared__ __align__(16) float xs[KK][CC][XROW];   // 39168 B -> 4 blocks/CU

    const int tid = threadIdx.x;
    const int bid = blockIdx.x;          // 2048 = seg(4) * h(256) * n(2)
    const int seg = bid & 3;
    const int h   = (bid >> 2) & 255;
    const int n   = bid >> 10;

    const int pxg = tid & 63;            // 64 groups of 2 px = 128 px
    const int cgr = tid >> 6;            // 4 channel-pairs
    const int c0  = cgr << 1;
    const int w0  = seg * SEGW + (pxg << 1);

    const int lane32 = tid & 31;         // staging: 8 channels x 32 lanes
    const int cstage = tid >> 5;
    const size_t HW = (size_t)HH * WW;
    const float* xc = x + ((size_t)(n * CC + cstage)) * HW;

    // ---- stage ALL 9 x rows (h-4..h+4), zero-padded; the ONLY barrier follows ----
    {
        const int wbody = seg * SEGW + (lane32 << 2);
        const int whalo = (lane32 == 0) ? (seg * SEGW - 4) : (seg * SEGW + SEGW);
        const int ihalo = (lane32 == 0) ? 0 : (XROW - 4);
        for (int r = 0; r < KK; ++r) {
            const int hh = h + r - 4;
            const bool rowok = (unsigned)hh < (unsigned)HH;
            const float* src = xc + (size_t)hh * WW;
            float4 sb = make_float4(0.f, 0.f, 0.f, 0.f);
            float4 sh = sb;
            if (rowok) sb = *(const float4*)(src + wbody);
            if (lane32 < 2 && rowok && (unsigned)whalo < (unsigned)WW)
                sh = *(const float4*)(src + whalo);
            *(float4*)&xs[r][cstage][4 + (lane32 << 2)] = sb;
            if (lane32 < 2) *(float4*)&xs[r][cstage][ihalo] = sh;
        }
    }

    const float* fptr = filt + ((size_t)(n * 81) * HH + h) * WW + w0;

    float a00, a01, a10, a11;
    {
        const float2 fb = *(const float2*)(fbias + ((size_t)(n * HH + h)) * WW + w0);
        a00 = fb.x; a01 = fb.y; a10 = fb.x; a11 = fb.y;
    }

    // prefetch iter-0 filters (land during the barrier drain)
    float2 f0 = *(const float2*)(fptr + 0 * HW);
    float2 f1 = *(const float2*)(fptr + 1 * HW);
    float2 f2 = *(const float2*)(fptr + 2 * HW);
    float2 f3 = *(const float2*)(fptr + 3 * HW);
    float2 f4 = *(const float2*)(fptr + 4 * HW);
    float2 f5 = *(const float2*)(fptr + 5 * HW);
    float2 f6 = *(const float2*)(fptr + 6 * HW);
    float2 f7 = *(const float2*)(fptr + 7 * HW);
    float2 f8 = *(const float2*)(fptr + 8 * HW);

    __syncthreads();   // single barrier in the whole kernel

    // prologue LDS reads for iter 0
    float2 u0, u1, u2, u3, u4, t0, t1, t2, t3, t4;
    {
        const float* xpa = &xs[0][c0][pxg << 1];
        const float* xpb = &xs[0][c0 + 1][pxg << 1];
        u0 = *(const float2*)(xpa + 0); u1 = *(const float2*)(xpa + 2);
        u2 = *(const float2*)(xpa + 4); u3 = *(const float2*)(xpa + 6);
        u4 = *(const float2*)(xpa + 8);
        t0 = *(const float2*)(xpb + 0); t1 = *(const float2*)(xpb + 2);
        t2 = *(const float2*)(xpb + 4); t3 = *(const float2*)(xpb + 6);
        t4 = *(const float2*)(xpb + 8);
    }

    // ---- barrier-free main loop, filters AND LDS reads software-pipelined ----
    // unroll(disable): auto-unroll hoists all 81 filter loads -> spill (R3-R5).
    // __launch_bounds__(256,4) -> 128-VGPR budget so both prefetch streams can
    // actually stay in flight (R8's 52-VGPR build serialized them).
    #pragma clang loop unroll(disable)
    for (int i = 0; i < KK; ++i) {
        const int inext = (i < KK - 1) ? i + 1 : i;   // uniform select, no branch

        // prefetch next iteration's filter taps (unconditional issue)
        float2 g0, g1, g2, g3, g4, g5, g6, g7, g8;
        {
            const float* fi = fptr + (size_t)inext * KK * HW;
            g0 = *(const float2*)(fi + 0 * HW);
            g1 = *(const float2*)(fi + 1 * HW);
            g2 = *(const float2*)(fi + 2 * HW);
            g3 = *(const float2*)(fi + 3 * HW);
            g4 = *(const float2*)(fi + 4 * HW);
            g5 = *(const float2*)(fi + 5 * HW);
            g6 = *(const float2*)(fi + 6 * HW);
            g7 = *(const float2*)(fi + 7 * HW);
            g8 = *(const float2*)(fi + 8 * HW);
        }

        // prefetch next iteration's LDS x-window
        float2 un0, un1, un2, un3, un4, tn0, tn1, tn2, tn3, tn4;
        {
            const float* xpa = &xs[inext][c0][pxg << 1];
            const float* xpb = &xs[inext][c0 + 1][pxg << 1];
            un0 = *(const float2*)(xpa + 0); un1 = *(const float2*)(xpa + 2);
            un2 = *(const float2*)(xpa + 4); un3 = *(const float2*)(xpa + 6);
            un4 = *(const float2*)(xpa + 8);
            tn0 = *(const float2*)(xpb + 0); tn1 = *(const float2*)(xpb + 2);
            tn2 = *(const float2*)(xpb + 4); tn3 = *(const float2*)(xpb + 6);
            tn4 = *(const float2*)(xpb + 8);
        }

        // compute with current filters + current x-window (all in registers)
        a00 = fmaf(f0.x, u0.x, a00);  a01 = fmaf(f0.y, u0.y, a01);
        a00 = fmaf(f1.x, u0.y, a00);  a01 = fmaf(f1.y, u1.x, a01);
        a00 = fmaf(f2.x, u1.x, a00);  a01 = fmaf(f2.y, u1.y, a01);
        a00 = fmaf(f3.x, u1.y, a00);  a01 = fmaf(f3.y, u2.x, a01);
        a00 = fmaf(f4.x, u2.x, a00);  a01 = fmaf(f4.y, u2.y, a01);
        a00 = fmaf(f5.x, u2.y, a00);  a01 = fmaf(f5.y, u3.x, a01);
        a00 = fmaf(f6.x, u3.x, a00);  a01 = fmaf(f6.y, u3.y, a01);
        a00 = fmaf(f7.x, u3.y, a00);  a01 = fmaf(f7.y, u4.x, a01);
        a00 = fmaf(f8.x, u4.x, a00);  a01 = fmaf(f8.y, u4.y, a01);

        a10 = fmaf(f0.x, t0.x, a10);  a11 = fmaf(f0.y, t0.y, a11);
        a10 = fmaf(f1.x, t0.y, a10);  a11 = fmaf(f1.y, t1.x, a11);
        a10 = fmaf(f2.x, t1.x, a10);  a11 = fmaf(f2.y, t1.y, a11);
        a10 = fmaf(f3.x, t1.y, a10);  a11 = fmaf(f3.y, t2.x, a11);
        a10 = fmaf(f4.x, t2.x, a10);  a11 = fmaf(f4.y, t2.y, a11);
        a10 = fmaf(f5.x, t2.y, a10);  a11 = fmaf(f5.y, t3.x, a11);
        a10 = fmaf(f6.x, t3.x, a10);  a11 = fmaf(f6.y, t3.y, a11);
        a10 = fmaf(f7.x, t3.y, a10);  a11 = fmaf(f7.y, t4.x, a11);
        a10 = fmaf(f8.x, t4.x, a10);  a11 = fmaf(f8.y, t4.y, a11);

        // rotate both pipelines
        f0 = g0; f1 = g1; f2 = g2; f3 = g3; f4 = g4;
        f5 = g5; f6 = g6; f7 = g7; f8 = g8;
        u0 = un0; u1 = un1; u2 = un2; u3 = un3; u4 = un4;
        t0 = tn0; t1 = tn1; t2 = tn2; t3 = tn3; t4 = tn4;
    }

    *(float2*)(out + ((size_t)(n * CC + c0) * HH + h) * WW + w0) = make_float2(a00, a01);
    *(float2*)(out + ((size_t)(n * CC + c0 + 1) * HH + h) * WW + w0) = make_float2(a10, a11);
}

extern "C" void kernel_launch(void* const* d_in, const int* in_sizes, int n_in,
                              void* d_out, int out_size, void* d_ws, size_t ws_size,
                              hipStream_t stream) {
    const float* x  = (const float*)d_in[0];
    const float* f  = (const float*)d_in[1];
    const float* fb = (const float*)d_in[2];
    float* o = (float*)d_out;
    hipLaunchKernelGGL(dynfilter_kernel, dim3(2048), dim3(256), 0, stream,
                       x, f, fb, o);
}